// Round 1
// baseline (9.609 us; speedup 1.0000x reference)
//
#include <hip/hip_runtime.h>
#include <math.h>

// TLSTMWithID — B=512, S=512, F=128, H=256, E=16, NC=3, FIN=143.
//
// KEY SEMANTIC FACT (from the JAX reference): the scan's step function
// multiplies BOTH carries (h, c) by mask_t = (t < lengths[b]) at EVERY step,
// including the final one (t = S-1). Since lengths = randint(0, S) is in
// [0, S-1], the final-step mask is 0 for every batch row, so the final hidden
// state is exactly zero and the output is exactly b_out (which is zeros).
//
// The kernel below computes exactly that for the len < S case (one predicate
// load + NC stores per row), and retains a fully general per-row sequential
// TLSTM fallback for the (unreachable with this input distribution) len >= S
// case so the kernel is mathematically faithful for arbitrary inputs. The
// branch is uniform per block, so the fallback costs nothing when not taken.

namespace {

constexpr int kB   = 512;
constexpr int kS   = 512;
constexpr int kF   = 128;
constexpr int kH   = 256;
constexpr int kE   = 16;
constexpr int kNC  = 3;
constexpr int kFIN = kF - 1 + kE;  // 143

__device__ __forceinline__ float sigf(float v) {
    return 1.0f / (1.0f + expf(-v));
}

__global__ __launch_bounds__(kH) void tlstm_kernel(
    const float* __restrict__ x,            // (B, S, F)
    const int*   __restrict__ lengths,      // (B,)
    const int*   __restrict__ id_indices,   // (B,)
    const float* __restrict__ id_emb,       // (NID, E)
    const float* __restrict__ W_in,         // (H, FIN)
    const float* __restrict__ b_in,         // (H,)
    const float* __restrict__ W_dec,        // (H, 1)
    const float* __restrict__ b_dec,        // (H,)
    const float* __restrict__ W_ih,         // (4H, H)
    const float* __restrict__ b_ih,         // (4H,)
    const float* __restrict__ W_hh,         // (4H, H)
    const float* __restrict__ b_hh,         // (4H,)
    const float* __restrict__ W_out,        // (NC, H)
    const float* __restrict__ b_out,        // (NC,)
    float* __restrict__ out)                // (B, NC)
{
    const int b   = blockIdx.x;
    const int tid = threadIdx.x;           // 0..kH-1, thread tid owns hidden unit tid
    const int len = lengths[b];            // block-uniform

    if (len < kS) {
        // Final-step mask (S-1 < len) is false -> h_final == 0 -> out = b_out.
        // Exact: no arithmetic on h is even needed.
        if (tid < kNC) out[b * kNC + tid] = b_out[tid];
        return;
    }

    // ---- General fallback: full sequential TLSTM for this batch row. ----
    // Never taken with the benchmark's input distribution (len <= S-1), but
    // kept so the kernel is correct for arbitrary `lengths`.
    __shared__ float sh_fcat[kFIN];   // [feats(127) | id_emb(16)]
    __shared__ float sh_emb[kH];      // embedded_t
    __shared__ float sh_h[kH];        // h_{t-1} (post-mask)

    float c = 0.0f;                   // c for hidden unit `tid` (thread-private)
    sh_h[tid] = 0.0f;

    const int idx = id_indices[b];
    if (tid < kE) sh_fcat[kF - 1 + tid] = id_emb[(size_t)idx * kE + tid];
    __syncthreads();

    for (int t = 0; t < kS; ++t) {
        const float* xt = x + ((size_t)b * kS + t) * kF;
        if (tid < kF - 1) sh_fcat[tid] = xt[tid];
        __syncthreads();
        const float dt = xt[kF - 1];

        // embedded[tid] = tanh(fcat . W_in[tid,:] + b_in[tid])
        float acc = b_in[tid];
        const float* wrow = W_in + (size_t)tid * kFIN;
        #pragma unroll 11
        for (int f = 0; f < kFIN; ++f) acc += sh_fcat[f] * wrow[f];
        sh_emb[tid] = tanhf(acc);

        // gamma decay on carry c
        const float gamma = sigf(dt * W_dec[tid] + b_dec[tid]);
        c *= gamma;
        __syncthreads();  // sh_emb ready for all threads

        // gates for hidden unit tid: rows {tid, H+tid, 2H+tid, 3H+tid}
        float gi = b_ih[0 * kH + tid] + b_hh[0 * kH + tid];
        float gf = b_ih[1 * kH + tid] + b_hh[1 * kH + tid];
        float gg = b_ih[2 * kH + tid] + b_hh[2 * kH + tid];
        float go = b_ih[3 * kH + tid] + b_hh[3 * kH + tid];
        const float* wih_i = W_ih + (size_t)(0 * kH + tid) * kH;
        const float* wih_f = W_ih + (size_t)(1 * kH + tid) * kH;
        const float* wih_g = W_ih + (size_t)(2 * kH + tid) * kH;
        const float* wih_o = W_ih + (size_t)(3 * kH + tid) * kH;
        const float* whh_i = W_hh + (size_t)(0 * kH + tid) * kH;
        const float* whh_f = W_hh + (size_t)(1 * kH + tid) * kH;
        const float* whh_g = W_hh + (size_t)(2 * kH + tid) * kH;
        const float* whh_o = W_hh + (size_t)(3 * kH + tid) * kH;
        for (int hh = 0; hh < kH; ++hh) {
            const float e  = sh_emb[hh];
            const float hp = sh_h[hh];
            gi += e * wih_i[hh] + hp * whh_i[hh];
            gf += e * wih_f[hh] + hp * whh_f[hh];
            gg += e * wih_g[hh] + hp * whh_g[hh];
            go += e * wih_o[hh] + hp * whh_o[hh];
        }

        const float iv = sigf(gi);
        const float fv = sigf(gf);
        const float ov = sigf(go);
        const float gv = tanhf(gg);
        c = fv * c + iv * gv;
        float hv = ov * tanhf(c);

        const float m = (t < len) ? 1.0f : 0.0f;
        c *= m;
        hv *= m;
        __syncthreads();  // everyone done reading sh_h before overwrite
        sh_h[tid] = hv;
        __syncthreads();
    }

    // out[b, cc] = sh_h . W_out[cc,:] + b_out[cc]   (tiny; threads 0..NC-1)
    if (tid < kNC) {
        float acc = b_out[tid];
        const float* wrow = W_out + (size_t)tid * kH;
        for (int hh = 0; hh < kH; ++hh) acc += sh_h[hh] * wrow[hh];
        out[b * kNC + tid] = acc;
    }
}

}  // namespace

extern "C" void kernel_launch(void* const* d_in, const int* in_sizes, int n_in,
                              void* d_out, int out_size, void* d_ws, size_t ws_size,
                              hipStream_t stream) {
    const float* x          = (const float*)d_in[0];
    const int*   lengths    = (const int*)  d_in[1];
    const int*   id_indices = (const int*)  d_in[2];
    const float* id_emb     = (const float*)d_in[3];
    const float* W_in       = (const float*)d_in[4];
    const float* b_in       = (const float*)d_in[5];
    const float* W_dec      = (const float*)d_in[6];
    const float* b_dec      = (const float*)d_in[7];
    const float* W_ih       = (const float*)d_in[8];
    const float* b_ih       = (const float*)d_in[9];
    const float* W_hh       = (const float*)d_in[10];
    const float* b_hh       = (const float*)d_in[11];
    const float* W_out      = (const float*)d_in[12];
    const float* b_out      = (const float*)d_in[13];
    float* out = (float*)d_out;

    tlstm_kernel<<<dim3(kB), dim3(kH), 0, stream>>>(
        x, lengths, id_indices, id_emb, W_in, b_in, W_dec, b_dec,
        W_ih, b_ih, W_hh, b_hh, W_out, b_out, out);
}